// Round 6
// baseline (236.571 us; speedup 1.0000x reference)
//
#include <hip/hip_runtime.h>
#include <hip/hip_bf16.h>
#include <cstdint>

// ---------- types ----------
typedef __bf16 bf16_t;
typedef __bf16 bf16x8 __attribute__((ext_vector_type(8)));
typedef __bf16 bf16x4 __attribute__((ext_vector_type(4)));
typedef float  floatx4 __attribute__((ext_vector_type(4)));

__device__ __forceinline__ bf16_t f2bf(float x) { return (bf16_t)x; }

// async global->LDS, 16B per lane; LDS dest = wave-uniform base + lane*16
__device__ __forceinline__ void gll16(const void* g, void* l) {
  __builtin_amdgcn_global_load_lds((const __attribute__((address_space(1))) void*)g,
                                   (__attribute__((address_space(3))) void*)l, 16, 0, 0);
}

#define S_LEN 2048
#define NHEAD 16
#define NTILE 32   // S_LEN / 64

// ---------- two W[K,N] fp32 -> Wt[N,K] bf16 in one launch ----------
__global__ __launch_bounds__(256) void transpose_w2(const float* __restrict__ W0,
                                                    const float* __restrict__ W1,
                                                    bf16_t* __restrict__ O0,
                                                    bf16_t* __restrict__ O1,
                                                    int K, int N) {
  const float* W = blockIdx.z ? W1 : W0;
  bf16_t* Wt = blockIdx.z ? O1 : O0;
  __shared__ float tile[32][33];
  int n0 = blockIdx.x * 32, k0 = blockIdx.y * 32;
  int tx = threadIdx.x & 31, ty = threadIdx.x >> 5;
#pragma unroll
  for (int r = 0; r < 4; ++r)
    tile[ty + 8 * r][tx] = W[(size_t)(k0 + ty + 8 * r) * N + n0 + tx];
  __syncthreads();
#pragma unroll
  for (int r = 0; r < 4; ++r)
    Wt[(size_t)(n0 + ty + 8 * r) * K + k0 + tx] = f2bf(tile[tx][ty + 8 * r]);
}

// ---------- big GEMM: 64x128 tile, BK=64, XOR-swizzled LDS ----------
// C[M,N] = A[M,K] * Bt[N,K]^T.
// OUTMODE: 0 = f32 out, 3 = bf16 out scaled by 0.125
// A_FP32: A is fp32, convert fused into staging (VGPR path); else bf16 via gll16.
template <int OUTMODE, bool A_FP32>
__global__ __launch_bounds__(256, 2) void gemm_async(const void* __restrict__ Ain,
                                                     const bf16_t* __restrict__ Bt,
                                                     void* __restrict__ Cout,
                                                     int M, int N, int K) {
  constexpr int BK = 64;
  __shared__ __align__(16) bf16_t As[64 * BK];    // 8 KB
  __shared__ __align__(16) bf16_t Bs[128 * BK];   // 16 KB
  const int tid = threadIdx.x;
  const int wave = tid >> 6, lane = tid & 63;
  const int quad = lane >> 4, lm = lane & 15;
  const int wr = wave >> 1, wc = wave & 1;  // wave tile: 32 rows x 64 cols
  const int m0 = blockIdx.x * 64, n0 = blockIdx.y * 128;

  floatx4 acc[2][4];
#pragma unroll
  for (int i = 0; i < 2; ++i)
#pragma unroll
    for (int j = 0; j < 4; ++j) acc[i][j] = (floatx4){0.f, 0.f, 0.f, 0.f};

  for (int k0 = 0; k0 < K; k0 += BK) {
    if constexpr (A_FP32) {
#pragma unroll
      for (int rd = 0; rd < 2; ++rd) {
        int idx = rd * 256 + tid, row = idx >> 3, ch = (idx & 7) ^ (row & 7);
        const float* src = (const float*)Ain + (size_t)(m0 + row) * K + k0 + ch * 8;
        float4 f0 = *(const float4*)src;
        float4 f1 = *(const float4*)(src + 4);
        bf16x8 o;
        o[0] = f2bf(f0.x); o[1] = f2bf(f0.y); o[2] = f2bf(f0.z); o[3] = f2bf(f0.w);
        o[4] = f2bf(f1.x); o[5] = f2bf(f1.y); o[6] = f2bf(f1.z); o[7] = f2bf(f1.w);
        *(bf16x8*)&As[idx * 8] = o;  // linear 16B/lane: conflict-free
      }
    } else {
#pragma unroll
      for (int rd = 0; rd < 2; ++rd) {
        int idx = rd * 256 + tid, row = idx >> 3, ch = (idx & 7) ^ (row & 7);
        gll16((const bf16_t*)Ain + (size_t)(m0 + row) * K + k0 + ch * 8,
              As + (rd * 256 + wave * 64) * 8);
      }
    }
#pragma unroll
    for (int rd = 0; rd < 4; ++rd) {
      int idx = rd * 256 + tid, row = idx >> 3, ch = (idx & 7) ^ (row & 7);
      gll16(Bt + (size_t)(n0 + row) * K + k0 + ch * 8,
            Bs + (rd * 256 + wave * 64) * 8);
    }
    __syncthreads();
    const int sw = lm & 7;
    bf16x8 af[2][2], bfr[4][2];
#pragma unroll
    for (int i = 0; i < 2; ++i) {
      const bf16_t* base = &As[(wr * 32 + i * 16 + lm) * BK];
      af[i][0] = *(const bf16x8*)(base + ((quad ^ sw) * 8));
      af[i][1] = *(const bf16x8*)(base + (((4 + quad) ^ sw) * 8));
    }
#pragma unroll
    for (int j = 0; j < 4; ++j) {
      const bf16_t* base = &Bs[(wc * 64 + j * 16 + lm) * BK];
      bfr[j][0] = *(const bf16x8*)(base + ((quad ^ sw) * 8));
      bfr[j][1] = *(const bf16x8*)(base + (((4 + quad) ^ sw) * 8));
    }
#pragma unroll
    for (int ks = 0; ks < 2; ++ks)
#pragma unroll
      for (int i = 0; i < 2; ++i)
#pragma unroll
        for (int j = 0; j < 4; ++j)
          acc[i][j] = __builtin_amdgcn_mfma_f32_16x16x32_bf16(af[i][ks], bfr[j][ks],
                                                              acc[i][j], 0, 0, 0);
    __syncthreads();
  }
#pragma unroll
  for (int i = 0; i < 2; ++i) {
#pragma unroll
    for (int j = 0; j < 4; ++j) {
      int row0 = m0 + wr * 32 + i * 16 + quad * 4;
      int col = n0 + wc * 64 + j * 16 + lm;
#pragma unroll
      for (int r = 0; r < 4; ++r) {
        if constexpr (OUTMODE == 3)
          ((bf16_t*)Cout)[(size_t)(row0 + r) * N + col] = f2bf(acc[i][j][r] * 0.125f);
        else
          ((float*)Cout)[(size_t)(row0 + r) * N + col] = acc[i][j][r];
      }
    }
  }
}

// ---------- K-proj + V-proj in ONE launch (blockIdx.z selects) ----------
__global__ __launch_bounds__(256) void gemm_kv(const float* __restrict__ Kin,
                                               const float* __restrict__ Vin,
                                               const bf16_t* __restrict__ Wkt,
                                               const bf16_t* __restrict__ Wvt,
                                               bf16_t* __restrict__ kp,
                                               bf16_t* __restrict__ vpt,
                                               int M, int K) {
  constexpr int BK = 32, LDK = 40, N = 64;
  const int isV = blockIdx.z;
  const float* A32 = isV ? Vin : Kin;
  const bf16_t* Bt = isV ? Wvt : Wkt;
  __shared__ __align__(16) bf16_t As[64 * LDK];
  __shared__ __align__(16) bf16_t Bs[64 * LDK];
  const int tid = threadIdx.x;
  const int wave = tid >> 6, lane = tid & 63;
  const int quad = lane >> 4, lm = lane & 15;
  const int wr = wave >> 1, wc = wave & 1;
  const int m0 = blockIdx.x * 64;

  floatx4 acc[2][2];
#pragma unroll
  for (int i = 0; i < 2; ++i)
#pragma unroll
    for (int j = 0; j < 2; ++j) acc[i][j] = (floatx4){0.f, 0.f, 0.f, 0.f};

  for (int k0 = 0; k0 < K; k0 += BK) {
    {
      int row = tid >> 2, c8 = tid & 3;
      const float* src = A32 + (size_t)(m0 + row) * K + k0 + c8 * 8;
      float4 f0 = *(const float4*)src;
      float4 f1 = *(const float4*)(src + 4);
      bf16x8 o;
      o[0] = f2bf(f0.x); o[1] = f2bf(f0.y); o[2] = f2bf(f0.z); o[3] = f2bf(f0.w);
      o[4] = f2bf(f1.x); o[5] = f2bf(f1.y); o[6] = f2bf(f1.z); o[7] = f2bf(f1.w);
      *(bf16x8*)&As[row * LDK + c8 * 8] = o;
    }
    {
      int row = tid >> 2, c8 = tid & 3;
      *(bf16x8*)&Bs[row * LDK + c8 * 8] =
          *(const bf16x8*)(Bt + (size_t)row * K + k0 + c8 * 8);
    }
    __syncthreads();
    bf16x8 af[2], bfr[2];
#pragma unroll
    for (int i = 0; i < 2; ++i)
      af[i] = *(const bf16x8*)&As[(wr * 32 + i * 16 + lm) * LDK + quad * 8];
#pragma unroll
    for (int j = 0; j < 2; ++j)
      bfr[j] = *(const bf16x8*)&Bs[(wc * 32 + j * 16 + lm) * LDK + quad * 8];
#pragma unroll
    for (int i = 0; i < 2; ++i)
#pragma unroll
      for (int j = 0; j < 2; ++j)
        acc[i][j] = __builtin_amdgcn_mfma_f32_16x16x32_bf16(af[i], bfr[j],
                                                            acc[i][j], 0, 0, 0);
    __syncthreads();
  }
#pragma unroll
  for (int i = 0; i < 2; ++i) {
#pragma unroll
    for (int j = 0; j < 2; ++j) {
      int row0 = m0 + wr * 32 + i * 16 + quad * 4;
      int col = wc * 32 + j * 16 + lm;
      if (isV) {
        bf16x4 o;
#pragma unroll
        for (int r = 0; r < 4; ++r) o[r] = f2bf(acc[i][j][r]);
        *(bf16x4*)&vpt[(size_t)col * M + row0] = o;
      } else {
#pragma unroll
        for (int r = 0; r < 4; ++r)
          kp[(size_t)(row0 + r) * N + col] = f2bf(acc[i][j][r]);
      }
    }
  }
}

// ---------- flash causal MQA, high arithmetic-intensity version ----------
// Wave owns 64 q-rows (4 subtiles; Q in registers as B-operands). Block =
// 2 waves = 2 HEADS sharing the K/V LDS tiles (MQA reuse). Each K/V/P
// b128 frag read now feeds 4 MFMAs (was 1): per-CU LDS pipe pressure
// drops ~2.7x per unit of work. S^T formulation, XOR-swizzled LDS,
// max-free softmax (q pre-scaled by 1/8), ones-MFMA row sums.
__global__ __launch_bounds__(128, 2) void flash_mqa(const bf16_t* __restrict__ q,   // [B*S,1024]
                                                    const bf16_t* __restrict__ kk,  // [B*S,64]
                                                    const bf16_t* __restrict__ vt,  // [64, B*S]
                                                    bf16_t* __restrict__ O,         // [B*S,1024]
                                                    int BStot) {
  const int qt = NTILE - 1 - blockIdx.x;  // heavy blocks dispatch first
  const int hb = blockIdx.y, b = blockIdx.z;
  const int tid = threadIdx.x;
  const int wave = tid >> 6, lane = tid & 63;
  const int quad = lane >> 4, lm = lane & 15;
  const int h = hb * 2 + wave;            // wave's head

  __shared__ __align__(16) bf16_t k_lds[2][64 * 64];   // 16 KB dbuf, [kj][d] swz
  __shared__ __align__(16) bf16_t v_lds[2][64 * 64];   // 16 KB dbuf, [dv][kj] swz
  __shared__ __align__(16) bf16_t p_lds[2][64 * 64];   // 16 KB, per-wave [q][kj] swz

  const size_t bS = (size_t)b * S_LEN;
  const int qb = qt * 64;
  const int sw = lm & 7;

  // Q fragments (MFMA B operand): lane holds Q[q = m*16+lm][d = quad*8+j]
  bf16x8 qf[4][2];
#pragma unroll
  for (int m = 0; m < 4; ++m) {
    const bf16_t* qp = q + (bS + qb + m * 16 + lm) * 1024 + h * 64;
    qf[m][0] = *(const bf16x8*)(qp + quad * 8);
    qf[m][1] = *(const bf16x8*)(qp + 32 + quad * 8);
  }
  bf16x8 onesf;
#pragma unroll
  for (int j = 0; j < 8; ++j) onesf[j] = f2bf(1.0f);

  floatx4 acc[4][4];   // [q-subtile][dv-subtile]
  floatx4 ps[4];       // row sums
#pragma unroll
  for (int m = 0; m < 4; ++m) {
    ps[m] = (floatx4){0.f, 0.f, 0.f, 0.f};
#pragma unroll
    for (int t = 0; t < 4; ++t) acc[m][t] = (floatx4){0.f, 0.f, 0.f, 0.f};
  }

  // staging: 4 rounds x 128 thr x 16B covers one 64x64 bf16 tile
  const int stid = tid;
  bf16x8 kst[4], vst[4];
  auto load_kv = [&](int kt) {
    const int k0 = kt * 64;
#pragma unroll
    for (int it = 0; it < 4; ++it) {
      int idx = it * 128 + stid, r = idx >> 3, c8 = idx & 7;
      kst[it] = *(const bf16x8*)(kk + (bS + k0 + r) * 64 + c8 * 8);
      vst[it] = *(const bf16x8*)(vt + (size_t)r * BStot + bS + k0 + c8 * 8);
    }
  };
  auto write_kv = [&](int buf) {
#pragma unroll
    for (int it = 0; it < 4; ++it) {
      int idx = it * 128 + stid, r = idx >> 3, c8 = idx & 7;
      int addr = r * 64 + ((c8 ^ (r & 7)) * 8);
      *(bf16x8*)&k_lds[buf][addr] = kst[it];
      *(bf16x8*)&v_lds[buf][addr] = vst[it];
    }
  };

  load_kv(0);
  write_kv(0);
  __syncthreads();

  for (int kt = 0; kt <= qt; ++kt) {
    const int cur = kt & 1;
    if (kt < qt) load_kv(kt + 1);  // prefetch into registers

    const bool diag = (kt == qt);
    // per kj-subtile t: read K A-frags once, use for 4 q-subtiles
#pragma unroll
    for (int t = 0; t < 4; ++t) {
      const bf16_t* kb = &k_lds[cur][(t * 16 + lm) * 64];
      bf16x8 a0 = *(const bf16x8*)(kb + ((quad ^ sw) * 8));
      bf16x8 a1 = *(const bf16x8*)(kb + (((4 + quad) ^ sw) * 8));
      floatx4 s[4];
#pragma unroll
      for (int m = 0; m < 4; ++m) {
        floatx4 cc = (floatx4){0.f, 0.f, 0.f, 0.f};
        cc = __builtin_amdgcn_mfma_f32_16x16x32_bf16(a0, qf[m][0], cc, 0, 0, 0);
        cc = __builtin_amdgcn_mfma_f32_16x16x32_bf16(a1, qf[m][1], cc, 0, 0, 0);
        s[m] = cc;
      }
      // mask (diagonal chunk only) + exp; then write P^T -> A-layout LDS
      if (diag) {
#pragma unroll
        for (int m = 0; m < 4; ++m) {
          int qq = m * 16 + lm;
#pragma unroll
          for (int r = 0; r < 4; ++r) {
            int kj = t * 16 + quad * 4 + r;
            s[m][r] = (kj <= qq) ? __expf(s[m][r]) : 0.f;
          }
        }
      } else {
#pragma unroll
        for (int m = 0; m < 4; ++m)
#pragma unroll
          for (int r = 0; r < 4; ++r) s[m][r] = __expf(s[m][r]);
      }
#pragma unroll
      for (int m = 0; m < 4; ++m) {
        bf16x4 pk;
#pragma unroll
        for (int r = 0; r < 4; ++r) pk[r] = f2bf(s[m][r]);
        *(bf16x4*)&p_lds[wave][(m * 16 + lm) * 64 +
                               (((2 * t + (quad >> 1)) ^ sw) * 8) + (quad & 1) * 4] = pk;
      }
    }
    // P A-frags (wave-private LDS, same-wave in-order: no barrier needed)
    bf16x8 p0[4], p1[4];
#pragma unroll
    for (int m = 0; m < 4; ++m) {
      const bf16_t* pb = &p_lds[wave][(m * 16 + lm) * 64];
      p0[m] = *(const bf16x8*)(pb + ((quad ^ sw) * 8));
      p1[m] = *(const bf16x8*)(pb + (((4 + quad) ^ sw) * 8));
      ps[m] = __builtin_amdgcn_mfma_f32_16x16x32_bf16(p0[m], onesf, ps[m], 0, 0, 0);
      ps[m] = __builtin_amdgcn_mfma_f32_16x16x32_bf16(p1[m], onesf, ps[m], 0, 0, 0);
    }
    // O += P.V : read V B-frags once per dv-subtile, use for 4 q-subtiles
#pragma unroll
    for (int t = 0; t < 4; ++t) {
      const bf16_t* vb = &v_lds[cur][(t * 16 + lm) * 64];
      bf16x8 v0 = *(const bf16x8*)(vb + ((quad ^ sw) * 8));
      bf16x8 v1 = *(const bf16x8*)(vb + (((4 + quad) ^ sw) * 8));
#pragma unroll
      for (int m = 0; m < 4; ++m) {
        acc[m][t] = __builtin_amdgcn_mfma_f32_16x16x32_bf16(p0[m], v0, acc[m][t], 0, 0, 0);
        acc[m][t] = __builtin_amdgcn_mfma_f32_16x16x32_bf16(p1[m], v1, acc[m][t], 0, 0, 0);
      }
    }
    if (kt < qt) write_kv(1 - cur);
    __syncthreads();
  }

  // epilogue: normalize by ones-MFMA row sums
#pragma unroll
  for (int m = 0; m < 4; ++m) {
    float rl[4];
#pragma unroll
    for (int r = 0; r < 4; ++r) rl[r] = 1.0f / ps[m][r];
    const int q0 = qb + m * 16 + quad * 4;
#pragma unroll
    for (int t = 0; t < 4; ++t)
#pragma unroll
      for (int r = 0; r < 4; ++r)
        O[(bS + q0 + r) * 1024 + h * 64 + t * 16 + lm] = f2bf(acc[m][t][r] * rl[r]);
  }
}

// ---------- launcher ----------
extern "C" void kernel_launch(void* const* d_in, const int* in_sizes, int n_in,
                              void* d_out, int out_size, void* d_ws, size_t ws_size,
                              hipStream_t stream) {
  const float* Q  = (const float*)d_in[0];
  const float* K  = (const float*)d_in[1];
  const float* V  = (const float*)d_in[2];
  const float* Wq = (const float*)d_in[3];
  const float* Wk = (const float*)d_in[4];
  const float* Wv = (const float*)d_in[5];
  const float* Wo = (const float*)d_in[6];

  const int BS = in_sizes[0] / 1024;  // B*S = 4096
  const int B  = BS / S_LEN;

  bf16_t* ws  = (bf16_t*)d_ws;
  bf16_t* qp  = ws;                              // q proj [BS,1024] (pre-scaled 1/8)
  bf16_t* Ob  = qp  + (size_t)BS * 1024;         // attn out [BS,1024]
  bf16_t* Wqt = Ob  + (size_t)BS * 1024;         // [1024,1024] (N,K)
  bf16_t* Wot = Wqt + (size_t)1024 * 1024;
  bf16_t* Wkt = Wot + (size_t)1024 * 1024;       // [64,1024]
  bf16_t* Wvt = Wkt + (size_t)64 * 1024;
  bf16_t* kp  = Wvt + (size_t)64 * 1024;         // [BS,64]
  bf16_t* vpt = kp  + (size_t)BS * 64;           // [64,BS]

  transpose_w2<<<dim3(32, 32, 2), 256, 0, stream>>>(Wq, Wo, Wqt, Wot, 1024, 1024);
  transpose_w2<<<dim3(2, 32, 2),  256, 0, stream>>>(Wk, Wv, Wkt, Wvt, 1024, 64);

  // K+V proj fused: 128 blocks
  gemm_kv<<<dim3(BS / 64, 1, 2), 256, 0, stream>>>(K, V, Wkt, Wvt, kp, vpt, BS, 1024);

  // Q-proj: fp32 A convert fused, output pre-scaled by 1/8
  gemm_async<3, true><<<dim3(BS / 64, 8), 256, 0, stream>>>(Q, Wqt, qp, BS, 1024, 1024);

  // flash: 128-thread blocks, 2 waves = 2 heads sharing K/V tiles
  flash_mqa<<<dim3(NTILE, NHEAD / 2, B), 128, 0, stream>>>(qp, kp, vpt, Ob, BS);

  // O-proj: f32 out
  gemm_async<0, false><<<dim3(BS / 64, 8), 256, 0, stream>>>(Ob, Wot, (float*)d_out, BS, 1024, 1024);
}

// Round 7
// 197.904 us; speedup vs baseline: 1.1954x; 1.1954x over previous
//
#include <hip/hip_runtime.h>
#include <hip/hip_bf16.h>
#include <cstdint>

// ---------- types ----------
typedef __bf16 bf16_t;
typedef __bf16 bf16x8 __attribute__((ext_vector_type(8)));
typedef __bf16 bf16x4 __attribute__((ext_vector_type(4)));
typedef float  floatx4 __attribute__((ext_vector_type(4)));

__device__ __forceinline__ bf16_t f2bf(float x) { return (bf16_t)x; }

// async global->LDS, 16B per lane; LDS dest = wave-uniform base + lane*16
__device__ __forceinline__ void gll16(const void* g, void* l) {
  __builtin_amdgcn_global_load_lds((const __attribute__((address_space(1))) void*)g,
                                   (__attribute__((address_space(3))) void*)l, 16, 0, 0);
}

#define S_LEN 2048
#define NHEAD 16

// ---------- ALL weight transposes in one launch ----------
// blocks [0,2048): Wq (z=0) / Wo (z=1), 1024x1024
// blocks [2048,2176): Wk (z=0) / Wv (z=1), 1024x64
__global__ __launch_bounds__(256) void transpose_all(const float* __restrict__ Wq,
                                                     const float* __restrict__ Wo,
                                                     const float* __restrict__ Wk,
                                                     const float* __restrict__ Wv,
                                                     bf16_t* __restrict__ Wqt,
                                                     bf16_t* __restrict__ Wot,
                                                     bf16_t* __restrict__ Wkt,
                                                     bf16_t* __restrict__ Wvt) {
  const int bid = blockIdx.x;
  const float* W; bf16_t* Wt; int n0, k0, N;
  if (bid < 2048) {
    int z = bid >> 10, rem = bid & 1023;
    W = z ? Wo : Wq; Wt = z ? Wot : Wqt;
    n0 = (rem & 31) * 32; k0 = (rem >> 5) * 32; N = 1024;
  } else {
    int b2 = bid - 2048, z = b2 >> 6, rem = b2 & 63;
    W = z ? Wv : Wk; Wt = z ? Wvt : Wkt;
    n0 = (rem & 1) * 32; k0 = (rem >> 1) * 32; N = 64;
  }
  const int K = 1024;
  __shared__ float tile[32][33];
  int tx = threadIdx.x & 31, ty = threadIdx.x >> 5;
#pragma unroll
  for (int r = 0; r < 4; ++r)
    tile[ty + 8 * r][tx] = W[(size_t)(k0 + ty + 8 * r) * N + n0 + tx];
  __syncthreads();
#pragma unroll
  for (int r = 0; r < 4; ++r)
    Wt[(size_t)(n0 + ty + 8 * r) * K + k0 + tx] = f2bf(tile[tx][ty + 8 * r]);
}

// ---------- big-GEMM device body: 64x128 tile, BK=64, XOR-swizzled LDS ----
// C[M,N] = A[M,K] * Bt[N,K]^T.  OUTMODE: 0 = f32, 3 = bf16 * 0.125
template <int OUTMODE, bool A_FP32>
__device__ __forceinline__ void gemm_body(const void* __restrict__ Ain,
                                          const bf16_t* __restrict__ Bt,
                                          void* __restrict__ Cout,
                                          int M, int N, int K,
                                          int m0, int n0,
                                          bf16_t* As, bf16_t* Bs) {
  constexpr int BK = 64;
  const int tid = threadIdx.x;
  const int wave = tid >> 6, lane = tid & 63;
  const int quad = lane >> 4, lm = lane & 15;
  const int wr = wave >> 1, wc = wave & 1;  // wave tile: 32 rows x 64 cols

  floatx4 acc[2][4];
#pragma unroll
  for (int i = 0; i < 2; ++i)
#pragma unroll
    for (int j = 0; j < 4; ++j) acc[i][j] = (floatx4){0.f, 0.f, 0.f, 0.f};

  for (int k0 = 0; k0 < K; k0 += BK) {
    if constexpr (A_FP32) {
#pragma unroll
      for (int rd = 0; rd < 2; ++rd) {
        int idx = rd * 256 + tid, row = idx >> 3, ch = (idx & 7) ^ (row & 7);
        const float* src = (const float*)Ain + (size_t)(m0 + row) * K + k0 + ch * 8;
        float4 f0 = *(const float4*)src;
        float4 f1 = *(const float4*)(src + 4);
        bf16x8 o;
        o[0] = f2bf(f0.x); o[1] = f2bf(f0.y); o[2] = f2bf(f0.z); o[3] = f2bf(f0.w);
        o[4] = f2bf(f1.x); o[5] = f2bf(f1.y); o[6] = f2bf(f1.z); o[7] = f2bf(f1.w);
        *(bf16x8*)&As[idx * 8] = o;
      }
    } else {
#pragma unroll
      for (int rd = 0; rd < 2; ++rd) {
        int idx = rd * 256 + tid, row = idx >> 3, ch = (idx & 7) ^ (row & 7);
        gll16((const bf16_t*)Ain + (size_t)(m0 + row) * K + k0 + ch * 8,
              As + (rd * 256 + wave * 64) * 8);
      }
    }
#pragma unroll
    for (int rd = 0; rd < 4; ++rd) {
      int idx = rd * 256 + tid, row = idx >> 3, ch = (idx & 7) ^ (row & 7);
      gll16(Bt + (size_t)(n0 + row) * K + k0 + ch * 8,
            Bs + (rd * 256 + wave * 64) * 8);
    }
    __syncthreads();
    const int sw = lm & 7;
    bf16x8 af[2][2], bfr[4][2];
#pragma unroll
    for (int i = 0; i < 2; ++i) {
      const bf16_t* base = &As[(wr * 32 + i * 16 + lm) * BK];
      af[i][0] = *(const bf16x8*)(base + ((quad ^ sw) * 8));
      af[i][1] = *(const bf16x8*)(base + (((4 + quad) ^ sw) * 8));
    }
#pragma unroll
    for (int j = 0; j < 4; ++j) {
      const bf16_t* base = &Bs[(wc * 64 + j * 16 + lm) * BK];
      bfr[j][0] = *(const bf16x8*)(base + ((quad ^ sw) * 8));
      bfr[j][1] = *(const bf16x8*)(base + (((4 + quad) ^ sw) * 8));
    }
#pragma unroll
    for (int ks = 0; ks < 2; ++ks)
#pragma unroll
      for (int i = 0; i < 2; ++i)
#pragma unroll
        for (int j = 0; j < 4; ++j)
          acc[i][j] = __builtin_amdgcn_mfma_f32_16x16x32_bf16(af[i][ks], bfr[j][ks],
                                                              acc[i][j], 0, 0, 0);
    __syncthreads();
  }
#pragma unroll
  for (int i = 0; i < 2; ++i) {
#pragma unroll
    for (int j = 0; j < 4; ++j) {
      int row0 = m0 + wr * 32 + i * 16 + quad * 4;
      int col = n0 + wc * 64 + j * 16 + lm;
#pragma unroll
      for (int r = 0; r < 4; ++r) {
        if constexpr (OUTMODE == 3)
          ((bf16_t*)Cout)[(size_t)(row0 + r) * N + col] = f2bf(acc[i][j][r] * 0.125f);
        else
          ((float*)Cout)[(size_t)(row0 + r) * N + col] = acc[i][j][r];
      }
    }
  }
}

// ---------- K/V-proj device body (64x64 tile, fused fp32->bf16) ----------
__device__ __forceinline__ void kv_body(const float* __restrict__ A32,
                                        const bf16_t* __restrict__ Bt,
                                        bf16_t* __restrict__ kp,
                                        bf16_t* __restrict__ vpt,
                                        int M, int K, int m0, int isV,
                                        bf16_t* As, bf16_t* Bs) {
  constexpr int BK = 32, LDK = 40, N = 64;
  const int tid = threadIdx.x;
  const int wave = tid >> 6, lane = tid & 63;
  const int quad = lane >> 4, lm = lane & 15;
  const int wr = wave >> 1, wc = wave & 1;

  floatx4 acc[2][2];
#pragma unroll
  for (int i = 0; i < 2; ++i)
#pragma unroll
    for (int j = 0; j < 2; ++j) acc[i][j] = (floatx4){0.f, 0.f, 0.f, 0.f};

  for (int k0 = 0; k0 < K; k0 += BK) {
    {
      int row = tid >> 2, c8 = tid & 3;
      const float* src = A32 + (size_t)(m0 + row) * K + k0 + c8 * 8;
      float4 f0 = *(const float4*)src;
      float4 f1 = *(const float4*)(src + 4);
      bf16x8 o;
      o[0] = f2bf(f0.x); o[1] = f2bf(f0.y); o[2] = f2bf(f0.z); o[3] = f2bf(f0.w);
      o[4] = f2bf(f1.x); o[5] = f2bf(f1.y); o[6] = f2bf(f1.z); o[7] = f2bf(f1.w);
      *(bf16x8*)&As[row * LDK + c8 * 8] = o;
    }
    {
      int row = tid >> 2, c8 = tid & 3;
      *(bf16x8*)&Bs[row * LDK + c8 * 8] =
          *(const bf16x8*)(Bt + (size_t)row * K + k0 + c8 * 8);
    }
    __syncthreads();
    bf16x8 af[2], bfr[2];
#pragma unroll
    for (int i = 0; i < 2; ++i)
      af[i] = *(const bf16x8*)&As[(wr * 32 + i * 16 + lm) * LDK + quad * 8];
#pragma unroll
    for (int j = 0; j < 2; ++j)
      bfr[j] = *(const bf16x8*)&Bs[(wc * 32 + j * 16 + lm) * LDK + quad * 8];
#pragma unroll
    for (int i = 0; i < 2; ++i)
#pragma unroll
      for (int j = 0; j < 2; ++j)
        acc[i][j] = __builtin_amdgcn_mfma_f32_16x16x32_bf16(af[i], bfr[j],
                                                            acc[i][j], 0, 0, 0);
    __syncthreads();
  }
#pragma unroll
  for (int i = 0; i < 2; ++i) {
#pragma unroll
    for (int j = 0; j < 2; ++j) {
      int row0 = m0 + wr * 32 + i * 16 + quad * 4;
      int col = wc * 32 + j * 16 + lm;
      if (isV) {
        bf16x4 o;
#pragma unroll
        for (int r = 0; r < 4; ++r) o[r] = f2bf(acc[i][j][r]);
        *(bf16x4*)&vpt[(size_t)col * M + row0] = o;
      } else {
#pragma unroll
        for (int r = 0; r < 4; ++r)
          kp[(size_t)(row0 + r) * N + col] = f2bf(acc[i][j][r]);
      }
    }
  }
}

// ---------- Q-proj + K-proj + V-proj in ONE launch ----------
// blocks [0, 512): Q-proj 64x128 tiles (bf16 out, pre-scaled 1/8)
// blocks [512, 640): K/V-proj 64x64 tiles
__global__ __launch_bounds__(256, 2) void proj_all(const float* __restrict__ Q,
                                                   const float* __restrict__ K,
                                                   const float* __restrict__ V,
                                                   const bf16_t* __restrict__ Wqt,
                                                   const bf16_t* __restrict__ Wkt,
                                                   const bf16_t* __restrict__ Wvt,
                                                   bf16_t* __restrict__ qp,
                                                   bf16_t* __restrict__ kp,
                                                   bf16_t* __restrict__ vpt,
                                                   int BS) {
  __shared__ __align__(16) bf16_t As[64 * 64];    // 8 KB
  __shared__ __align__(16) bf16_t Bs[128 * 64];   // 16 KB
  const int bid = blockIdx.x;
  const int nQ = (BS / 64) * 8;
  if (bid < nQ) {
    int m0 = (bid & (BS / 64 - 1)) * 64, n0 = (bid / (BS / 64)) * 128;
    gemm_body<3, true>(Q, Wqt, qp, BS, 1024, 1024, m0, n0, As, Bs);
  } else {
    int b2 = bid - nQ;
    int isV = (b2 >= BS / 64);
    int m0 = (b2 & (BS / 64 - 1)) * 64;
    kv_body(isV ? V : K, isV ? Wvt : Wkt, kp, vpt, BS, 1024, m0, isV, As, Bs);
  }
}

// ---------- O-proj ----------
__global__ __launch_bounds__(256, 2) void gemm_oproj(const bf16_t* __restrict__ A,
                                                     const bf16_t* __restrict__ Bt,
                                                     float* __restrict__ Cout,
                                                     int M, int N, int K) {
  __shared__ __align__(16) bf16_t As[64 * 64];
  __shared__ __align__(16) bf16_t Bs[128 * 64];
  gemm_body<0, false>(A, Bt, Cout, M, N, K,
                      blockIdx.x * 64, blockIdx.y * 128, As, Bs);
}

// ---------- flash causal MQA ----------
// Wave owns 32 q-rows (2 subtiles) of its OWN head; block = 4 waves = 4
// heads sharing the K/V LDS tiles (MQA reuse x4 on staging). 2048 waves
// total = 8/CU (2 blocks/CU co-resident). S^T formulation, XOR-swizzled
// LDS, max-free softmax (q pre-scaled 1/8), ones-MFMA row sums,
// register-prefetch double-buffered staging (1 barrier/iter).
__global__ __launch_bounds__(256, 2) void flash_mqa(const bf16_t* __restrict__ q,   // [B*S,1024]
                                                    const bf16_t* __restrict__ kk,  // [B*S,64]
                                                    const bf16_t* __restrict__ vt,  // [64, B*S]
                                                    bf16_t* __restrict__ O,         // [B*S,1024]
                                                    int BStot) {
  const int qt = 63 - blockIdx.x;        // 32-row q-tile, heavy first
  const int hg = blockIdx.y, b = blockIdx.z;
  const int tid = threadIdx.x;
  const int wave = tid >> 6, lane = tid & 63;
  const int quad = lane >> 4, lm = lane & 15;
  const int h = hg * 4 + wave;           // wave's head

  __shared__ __align__(16) bf16_t k_lds[2][64 * 64];   // 16 KB dbuf [kj][d] swz
  __shared__ __align__(16) bf16_t v_lds[2][64 * 64];   // 16 KB dbuf [dv][kj] swz
  __shared__ __align__(16) bf16_t p_lds[4][32 * 64];   // 16 KB per-wave [q][kj] swz

  const size_t bS = (size_t)b * S_LEN;
  const int qb = qt * 32;
  const int ktmax = qt >> 1;
  const int qoff = qb - ktmax * 64;      // 0 (qt even) or 32 (qt odd)
  const int sw = lm & 7;

  // Q fragments (MFMA B operand): lane holds Q[q=m*16+lm][d=quad*8+j]
  bf16x8 qf[2][2];
#pragma unroll
  for (int m = 0; m < 2; ++m) {
    const bf16_t* qp = q + (bS + qb + m * 16 + lm) * 1024 + h * 64;
    qf[m][0] = *(const bf16x8*)(qp + quad * 8);
    qf[m][1] = *(const bf16x8*)(qp + 32 + quad * 8);
  }
  bf16x8 onesf;
#pragma unroll
  for (int j = 0; j < 8; ++j) onesf[j] = f2bf(1.0f);

  floatx4 acc[2][4];   // [q-subtile][dv-subtile]
  floatx4 ps[2];       // row sums
#pragma unroll
  for (int m = 0; m < 2; ++m) {
    ps[m] = (floatx4){0.f, 0.f, 0.f, 0.f};
#pragma unroll
    for (int t = 0; t < 4; ++t) acc[m][t] = (floatx4){0.f, 0.f, 0.f, 0.f};
  }

  // staging: 2 rounds x 256 thr x 16B per 64x64 tile
  bf16x8 kst[2], vst[2];
  auto load_kv = [&](int kt) {
    const int k0 = kt * 64;
#pragma unroll
    for (int it = 0; it < 2; ++it) {
      int idx = it * 256 + tid, r = idx >> 3, c8 = idx & 7;
      kst[it] = *(const bf16x8*)(kk + (bS + k0 + r) * 64 + c8 * 8);
      vst[it] = *(const bf16x8*)(vt + (size_t)r * BStot + bS + k0 + c8 * 8);
    }
  };
  auto write_kv = [&](int buf) {
#pragma unroll
    for (int it = 0; it < 2; ++it) {
      int idx = it * 256 + tid, r = idx >> 3, c8 = idx & 7;
      int addr = r * 64 + ((c8 ^ (r & 7)) * 8);
      *(bf16x8*)&k_lds[buf][addr] = kst[it];
      *(bf16x8*)&v_lds[buf][addr] = vst[it];
    }
  };

  load_kv(0);
  write_kv(0);
  __syncthreads();

  for (int kt = 0; kt <= ktmax; ++kt) {
    const int cur = kt & 1;
    if (kt < ktmax) load_kv(kt + 1);  // prefetch into registers
    const bool diag = (kt == ktmax);

    // S^T = K.Q^T per kj-subtile t; K A-frags reused for 2 q-subtiles
#pragma unroll
    for (int t = 0; t < 4; ++t) {
      const bf16_t* kb = &k_lds[cur][(t * 16 + lm) * 64];
      bf16x8 a0 = *(const bf16x8*)(kb + ((quad ^ sw) * 8));
      bf16x8 a1 = *(const bf16x8*)(kb + (((4 + quad) ^ sw) * 8));
      floatx4 s[2];
#pragma unroll
      for (int m = 0; m < 2; ++m) {
        floatx4 cc = (floatx4){0.f, 0.f, 0.f, 0.f};
        cc = __builtin_amdgcn_mfma_f32_16x16x32_bf16(a0, qf[m][0], cc, 0, 0, 0);
        cc = __builtin_amdgcn_mfma_f32_16x16x32_bf16(a1, qf[m][1], cc, 0, 0, 0);
        s[m] = cc;
      }
      if (diag) {
#pragma unroll
        for (int m = 0; m < 2; ++m) {
          int qq = qoff + m * 16 + lm;
#pragma unroll
          for (int r = 0; r < 4; ++r) {
            int kj = t * 16 + quad * 4 + r;
            s[m][r] = (kj <= qq) ? __expf(s[m][r]) : 0.f;
          }
        }
      } else {
#pragma unroll
        for (int m = 0; m < 2; ++m)
#pragma unroll
          for (int r = 0; r < 4; ++r) s[m][r] = __expf(s[m][r]);
      }
      // P^T (C-layout) -> p_lds in swizzled A-layout
#pragma unroll
      for (int m = 0; m < 2; ++m) {
        bf16x4 pk;
#pragma unroll
        for (int r = 0; r < 4; ++r) pk[r] = f2bf(s[m][r]);
        *(bf16x4*)&p_lds[wave][(m * 16 + lm) * 64 +
                               (((2 * t + (quad >> 1)) ^ sw) * 8) + (quad & 1) * 4] = pk;
      }
    }
    // P A-frags (wave-private LDS, same-wave in-order: no barrier)
    bf16x8 p0[2], p1[2];
#pragma unroll
    for (int m = 0; m < 2; ++m) {
      const bf16_t* pb = &p_lds[wave][(m * 16 + lm) * 64];
      p0[m] = *(const bf16x8*)(pb + ((quad ^ sw) * 8));
      p1[m] = *(const bf16x8*)(pb + (((4 + quad) ^ sw) * 8));
      ps[m] = __builtin_amdgcn_mfma_f32_16x16x32_bf16(p0[m], onesf, ps[m], 0, 0, 0);
      ps[m] = __builtin_amdgcn_mfma_f32_16x16x32_bf16(p1[m], onesf, ps[m], 0, 0, 0);
    }
    // O += P.V : V B-frags reused for 2 q-subtiles
#pragma unroll
    for (int t = 0; t < 4; ++t) {
      const bf16_t* vb = &v_lds[cur][(t * 16 + lm) * 64];
      bf16x8 v0 = *(const bf16x8*)(vb + ((quad ^ sw) * 8));
      bf16x8 v1 = *(const bf16x8*)(vb + (((4 + quad) ^ sw) * 8));
#pragma unroll
      for (int m = 0; m < 2; ++m) {
        acc[m][t] = __builtin_amdgcn_mfma_f32_16x16x32_bf16(p0[m], v0, acc[m][t], 0, 0, 0);
        acc[m][t] = __builtin_amdgcn_mfma_f32_16x16x32_bf16(p1[m], v1, acc[m][t], 0, 0, 0);
      }
    }
    if (kt < ktmax) write_kv(1 - cur);
    __syncthreads();
  }

  // epilogue: normalize by ones-MFMA row sums
#pragma unroll
  for (int m = 0; m < 2; ++m) {
    float rl[4];
#pragma unroll
    for (int r = 0; r < 4; ++r) rl[r] = 1.0f / ps[m][r];
    const int q0 = qb + m * 16 + quad * 4;
#pragma unroll
    for (int t = 0; t < 4; ++t)
#pragma unroll
      for (int r = 0; r < 4; ++r)
        O[(bS + q0 + r) * 1024 + h * 64 + t * 16 + lm] = f2bf(acc[m][t][r] * rl[r]);
  }
}

// ---------- launcher ----------
extern "C" void kernel_launch(void* const* d_in, const int* in_sizes, int n_in,
                              void* d_out, int out_size, void* d_ws, size_t ws_size,
                              hipStream_t stream) {
  const float* Q  = (const float*)d_in[0];
  const float* K  = (const float*)d_in[1];
  const float* V  = (const float*)d_in[2];
  const float* Wq = (const float*)d_in[3];
  const float* Wk = (const float*)d_in[4];
  const float* Wv = (const float*)d_in[5];
  const float* Wo = (const float*)d_in[6];

  const int BS = in_sizes[0] / 1024;  // B*S = 4096
  const int B  = BS / S_LEN;

  bf16_t* ws  = (bf16_t*)d_ws;
  bf16_t* qp  = ws;                              // q proj [BS,1024] (pre-scaled 1/8)
  bf16_t* Ob  = qp  + (size_t)BS * 1024;         // attn out [BS,1024]
  bf16_t* Wqt = Ob  + (size_t)BS * 1024;         // [1024,1024] (N,K)
  bf16_t* Wot = Wqt + (size_t)1024 * 1024;
  bf16_t* Wkt = Wot + (size_t)1024 * 1024;       // [64,1024]
  bf16_t* Wvt = Wkt + (size_t)64 * 1024;
  bf16_t* kp  = Wvt + (size_t)64 * 1024;         // [BS,64]
  bf16_t* vpt = kp  + (size_t)BS * 64;           // [64,BS]

  // 1) all weight transposes
  transpose_all<<<2176, 256, 0, stream>>>(Wq, Wo, Wk, Wv, Wqt, Wot, Wkt, Wvt);

  // 2) Q-proj + K-proj + V-proj (640 blocks, co-scheduled)
  proj_all<<<(BS / 64) * 8 + (BS / 64) * 2, 256, 0, stream>>>(
      Q, K, V, Wqt, Wkt, Wvt, qp, kp, vpt, BS);

  // 3) flash attention: 512 blocks x 4 waves (4 heads sharing K/V tiles)
  flash_mqa<<<dim3(S_LEN / 32, NHEAD / 4, B), 256, 0, stream>>>(qp, kp, vpt, Ob, BS);

  // 4) O-proj (f32 out)
  gemm_oproj<<<dim3(BS / 64, 8), 256, 0, stream>>>(Ob, Wot, (float*)d_out, BS, 1024, 1024);
}

// Round 8
// 192.779 us; speedup vs baseline: 1.2272x; 1.0266x over previous
//
#include <hip/hip_runtime.h>
#include <hip/hip_bf16.h>
#include <cstdint>

// ---------- types ----------
typedef __bf16 bf16_t;
typedef __bf16 bf16x8 __attribute__((ext_vector_type(8)));
typedef __bf16 bf16x4 __attribute__((ext_vector_type(4)));
typedef float  floatx4 __attribute__((ext_vector_type(4)));

__device__ __forceinline__ bf16_t f2bf(float x) { return (bf16_t)x; }

// async global->LDS, 16B per lane; LDS dest = wave-uniform base + lane*16
__device__ __forceinline__ void gll16(const void* g, void* l) {
  __builtin_amdgcn_global_load_lds((const __attribute__((address_space(1))) void*)g,
                                   (__attribute__((address_space(3))) void*)l, 16, 0, 0);
}

#define S_LEN 2048
#define NHEAD 16

// ---------- ALL weight transposes in one launch ----------
__global__ __launch_bounds__(256) void transpose_all(const float* __restrict__ Wq,
                                                     const float* __restrict__ Wo,
                                                     const float* __restrict__ Wk,
                                                     const float* __restrict__ Wv,
                                                     bf16_t* __restrict__ Wqt,
                                                     bf16_t* __restrict__ Wot,
                                                     bf16_t* __restrict__ Wkt,
                                                     bf16_t* __restrict__ Wvt) {
  const int bid = blockIdx.x;
  const float* W; bf16_t* Wt; int n0, k0, N;
  if (bid < 2048) {
    int z = bid >> 10, rem = bid & 1023;
    W = z ? Wo : Wq; Wt = z ? Wot : Wqt;
    n0 = (rem & 31) * 32; k0 = (rem >> 5) * 32; N = 1024;
  } else {
    int b2 = bid - 2048, z = b2 >> 6, rem = b2 & 63;
    W = z ? Wv : Wk; Wt = z ? Wvt : Wkt;
    n0 = (rem & 1) * 32; k0 = (rem >> 1) * 32; N = 64;
  }
  const int K = 1024;
  __shared__ float tile[32][33];
  int tx = threadIdx.x & 31, ty = threadIdx.x >> 5;
#pragma unroll
  for (int r = 0; r < 4; ++r)
    tile[ty + 8 * r][tx] = W[(size_t)(k0 + ty + 8 * r) * N + n0 + tx];
  __syncthreads();
#pragma unroll
  for (int r = 0; r < 4; ++r)
    Wt[(size_t)(n0 + ty + 8 * r) * K + k0 + tx] = f2bf(tile[tx][ty + 8 * r]);
}

// ---------- big-GEMM device body: 64x128 tile, BK=64, XOR-swizzled LDS ----
// C[M,N] = A[M,K] * Bt[N,K]^T.  OUTMODE: 0 = f32, 3 = bf16 * 0.125
template <int OUTMODE, bool A_FP32>
__device__ __forceinline__ void gemm_body(const void* __restrict__ Ain,
                                          const bf16_t* __restrict__ Bt,
                                          void* __restrict__ Cout,
                                          int M, int N, int K,
                                          int m0, int n0,
                                          bf16_t* As, bf16_t* Bs) {
  constexpr int BK = 64;
  const int tid = threadIdx.x;
  const int wave = tid >> 6, lane = tid & 63;
  const int quad = lane >> 4, lm = lane & 15;
  const int wr = wave >> 1, wc = wave & 1;  // wave tile: 32 rows x 64 cols

  floatx4 acc[2][4];
#pragma unroll
  for (int i = 0; i < 2; ++i)
#pragma unroll
    for (int j = 0; j < 4; ++j) acc[i][j] = (floatx4){0.f, 0.f, 0.f, 0.f};

  for (int k0 = 0; k0 < K; k0 += BK) {
    if constexpr (A_FP32) {
#pragma unroll
      for (int rd = 0; rd < 2; ++rd) {
        int idx = rd * 256 + tid, row = idx >> 3, ch = (idx & 7) ^ (row & 7);
        const float* src = (const float*)Ain + (size_t)(m0 + row) * K + k0 + ch * 8;
        float4 f0 = *(const float4*)src;
        float4 f1 = *(const float4*)(src + 4);
        bf16x8 o;
        o[0] = f2bf(f0.x); o[1] = f2bf(f0.y); o[2] = f2bf(f0.z); o[3] = f2bf(f0.w);
        o[4] = f2bf(f1.x); o[5] = f2bf(f1.y); o[6] = f2bf(f1.z); o[7] = f2bf(f1.w);
        *(bf16x8*)&As[idx * 8] = o;
      }
    } else {
#pragma unroll
      for (int rd = 0; rd < 2; ++rd) {
        int idx = rd * 256 + tid, row = idx >> 3, ch = (idx & 7) ^ (row & 7);
        gll16((const bf16_t*)Ain + (size_t)(m0 + row) * K + k0 + ch * 8,
              As + (rd * 256 + wave * 64) * 8);
      }
    }
#pragma unroll
    for (int rd = 0; rd < 4; ++rd) {
      int idx = rd * 256 + tid, row = idx >> 3, ch = (idx & 7) ^ (row & 7);
      gll16(Bt + (size_t)(n0 + row) * K + k0 + ch * 8,
            Bs + (rd * 256 + wave * 64) * 8);
    }
    __syncthreads();
    const int sw = lm & 7;
    bf16x8 af[2][2], bfr[4][2];
#pragma unroll
    for (int i = 0; i < 2; ++i) {
      const bf16_t* base = &As[(wr * 32 + i * 16 + lm) * BK];
      af[i][0] = *(const bf16x8*)(base + ((quad ^ sw) * 8));
      af[i][1] = *(const bf16x8*)(base + (((4 + quad) ^ sw) * 8));
    }
#pragma unroll
    for (int j = 0; j < 4; ++j) {
      const bf16_t* base = &Bs[(wc * 64 + j * 16 + lm) * BK];
      bfr[j][0] = *(const bf16x8*)(base + ((quad ^ sw) * 8));
      bfr[j][1] = *(const bf16x8*)(base + (((4 + quad) ^ sw) * 8));
    }
#pragma unroll
    for (int ks = 0; ks < 2; ++ks)
#pragma unroll
      for (int i = 0; i < 2; ++i)
#pragma unroll
        for (int j = 0; j < 4; ++j)
          acc[i][j] = __builtin_amdgcn_mfma_f32_16x16x32_bf16(af[i][ks], bfr[j][ks],
                                                              acc[i][j], 0, 0, 0);
    __syncthreads();
  }
#pragma unroll
  for (int i = 0; i < 2; ++i) {
#pragma unroll
    for (int j = 0; j < 4; ++j) {
      int row0 = m0 + wr * 32 + i * 16 + quad * 4;
      int col = n0 + wc * 64 + j * 16 + lm;
#pragma unroll
      for (int r = 0; r < 4; ++r) {
        if constexpr (OUTMODE == 3)
          ((bf16_t*)Cout)[(size_t)(row0 + r) * N + col] = f2bf(acc[i][j][r] * 0.125f);
        else
          ((float*)Cout)[(size_t)(row0 + r) * N + col] = acc[i][j][r];
      }
    }
  }
}

// ---------- K/V-proj device body (64x64 tile, fused fp32->bf16) ----------
__device__ __forceinline__ void kv_body(const float* __restrict__ A32,
                                        const bf16_t* __restrict__ Bt,
                                        bf16_t* __restrict__ kp,
                                        bf16_t* __restrict__ vpt,
                                        int M, int K, int m0, int isV,
                                        bf16_t* As, bf16_t* Bs) {
  constexpr int BK = 32, LDK = 40, N = 64;
  const int tid = threadIdx.x;
  const int wave = tid >> 6, lane = tid & 63;
  const int quad = lane >> 4, lm = lane & 15;
  const int wr = wave >> 1, wc = wave & 1;

  floatx4 acc[2][2];
#pragma unroll
  for (int i = 0; i < 2; ++i)
#pragma unroll
    for (int j = 0; j < 2; ++j) acc[i][j] = (floatx4){0.f, 0.f, 0.f, 0.f};

  for (int k0 = 0; k0 < K; k0 += BK) {
    {
      int row = tid >> 2, c8 = tid & 3;
      const float* src = A32 + (size_t)(m0 + row) * K + k0 + c8 * 8;
      float4 f0 = *(const float4*)src;
      float4 f1 = *(const float4*)(src + 4);
      bf16x8 o;
      o[0] = f2bf(f0.x); o[1] = f2bf(f0.y); o[2] = f2bf(f0.z); o[3] = f2bf(f0.w);
      o[4] = f2bf(f1.x); o[5] = f2bf(f1.y); o[6] = f2bf(f1.z); o[7] = f2bf(f1.w);
      *(bf16x8*)&As[row * LDK + c8 * 8] = o;
    }
    {
      int row = tid >> 2, c8 = tid & 3;
      *(bf16x8*)&Bs[row * LDK + c8 * 8] =
          *(const bf16x8*)(Bt + (size_t)row * K + k0 + c8 * 8);
    }
    __syncthreads();
    bf16x8 af[2], bfr[2];
#pragma unroll
    for (int i = 0; i < 2; ++i)
      af[i] = *(const bf16x8*)&As[(wr * 32 + i * 16 + lm) * LDK + quad * 8];
#pragma unroll
    for (int j = 0; j < 2; ++j)
      bfr[j] = *(const bf16x8*)&Bs[(wc * 32 + j * 16 + lm) * LDK + quad * 8];
#pragma unroll
    for (int i = 0; i < 2; ++i)
#pragma unroll
      for (int j = 0; j < 2; ++j)
        acc[i][j] = __builtin_amdgcn_mfma_f32_16x16x32_bf16(af[i], bfr[j],
                                                            acc[i][j], 0, 0, 0);
    __syncthreads();
  }
#pragma unroll
  for (int i = 0; i < 2; ++i) {
#pragma unroll
    for (int j = 0; j < 2; ++j) {
      int row0 = m0 + wr * 32 + i * 16 + quad * 4;
      int col = wc * 32 + j * 16 + lm;
      if (isV) {
        bf16x4 o;
#pragma unroll
        for (int r = 0; r < 4; ++r) o[r] = f2bf(acc[i][j][r]);
        *(bf16x4*)&vpt[(size_t)col * M + row0] = o;
      } else {
#pragma unroll
        for (int r = 0; r < 4; ++r)
          kp[(size_t)(row0 + r) * N + col] = f2bf(acc[i][j][r]);
      }
    }
  }
}

// ---------- Q-proj + K-proj + V-proj in ONE launch ----------
__global__ __launch_bounds__(256, 2) void proj_all(const float* __restrict__ Q,
                                                   const float* __restrict__ K,
                                                   const float* __restrict__ V,
                                                   const bf16_t* __restrict__ Wqt,
                                                   const bf16_t* __restrict__ Wkt,
                                                   const bf16_t* __restrict__ Wvt,
                                                   bf16_t* __restrict__ qp,
                                                   bf16_t* __restrict__ kp,
                                                   bf16_t* __restrict__ vpt,
                                                   int BS) {
  __shared__ __align__(16) bf16_t As[64 * 64];    // 8 KB
  __shared__ __align__(16) bf16_t Bs[128 * 64];   // 16 KB
  const int bid = blockIdx.x;
  const int nQ = (BS / 64) * 8;
  if (bid < nQ) {
    int m0 = (bid & (BS / 64 - 1)) * 64, n0 = (bid / (BS / 64)) * 128;
    gemm_body<3, true>(Q, Wqt, qp, BS, 1024, 1024, m0, n0, As, Bs);
  } else {
    int b2 = bid - nQ;
    int isV = (b2 >= BS / 64);
    int m0 = (b2 & (BS / 64 - 1)) * 64;
    kv_body(isV ? V : K, isV ? Wvt : Wkt, kp, vpt, BS, 1024, m0, isV, As, Bs);
  }
}

// ---------- O-proj ----------
__global__ __launch_bounds__(256, 2) void gemm_oproj(const bf16_t* __restrict__ A,
                                                     const bf16_t* __restrict__ Bt,
                                                     float* __restrict__ Cout,
                                                     int M, int N, int K) {
  __shared__ __align__(16) bf16_t As[64 * 64];
  __shared__ __align__(16) bf16_t Bs[128 * 64];
  gemm_body<0, false>(A, Bt, Cout, M, N, K,
                      blockIdx.x * 64, blockIdx.y * 128, As, Bs);
}

// ---------- flash causal MQA, k-chunked (additive partial softmax) --------
// The max-free softmax is ADDITIVE over k-subranges: O_p = sum exp(s)V and
// l_p = sum exp(s) combine by summation. Each block handles an 8-k-iter
// chunk of one 32-row q-tile for 4 heads -> 1280 near-uniform blocks
// (span was the R7 limiter: 33-iter heavy blocks vs 4.25 iters/CU of work).
// Partials (unnormalized bf16 O + f32 l) land in one of 4 slot buffers;
// s==0 blocks zero unused slots; combine_o sums/normalizes.
// Flat chunk decode over 160 slots:
//   qt 0..15: 1 chunk; 16..31: 2; 32..47: 3; 48..63: 4   (n = qt/2+1 iters)
__global__ __launch_bounds__(256, 2) void flash_mqa(const bf16_t* __restrict__ q,   // [B*S,1024], pre-scaled 1/8
                                                    const bf16_t* __restrict__ kk,  // [B*S,64]
                                                    const bf16_t* __restrict__ vt,  // [64, B*S]
                                                    bf16_t* __restrict__ Opart,     // 4 x [B*S,1024]
                                                    float* __restrict__ lpart,      // 4 x [B*S,16]
                                                    int BStot) {
  // ---- decode (qt, s) from flat chunk id ----
  const int c = blockIdx.x;
  int qt, s;
  if (c < 16)      { qt = c; s = 0; }
  else if (c < 48) { qt = 16 + ((c - 16) >> 1); s = (c - 16) & 1; }
  else if (c < 96) { int d = c - 48; int q3 = d / 3; qt = 32 + q3; s = d - q3 * 3; }
  else             { qt = 48 + ((c - 96) >> 2); s = (c - 96) & 3; }
  const int n = (qt >> 1) + 1;          // total k-iters for this q-tile
  const int nchunks = (n + 7) >> 3;
  const int kt0 = s * 8;
  const int kt1 = (kt0 + 8 < n) ? kt0 + 8 : n;
  const int ktmax = n - 1;              // global diagonal iter

  const int hg = blockIdx.y, b = blockIdx.z;
  const int tid = threadIdx.x;
  const int wave = tid >> 6, lane = tid & 63;
  const int quad = lane >> 4, lm = lane & 15;
  const int h = hg * 4 + wave;          // wave's head

  __shared__ __align__(16) bf16_t k_lds[2][64 * 64];   // 16 KB dbuf [kj][d] swz
  __shared__ __align__(16) bf16_t v_lds[2][64 * 64];   // 16 KB dbuf [dv][kj] swz
  __shared__ __align__(16) bf16_t p_lds[4][32 * 64];   // 16 KB per-wave [q][kj] swz

  const size_t bS = (size_t)b * S_LEN;
  const int qb = qt * 32;
  const int qoff = qb - ktmax * 64;     // 0 (qt even) or 32 (qt odd)
  const int sw = lm & 7;

  // Q fragments (MFMA B operand): lane holds Q[q=m*16+lm][d=quad*8+j]
  bf16x8 qf[2][2];
#pragma unroll
  for (int m = 0; m < 2; ++m) {
    const bf16_t* qp = q + (bS + qb + m * 16 + lm) * 1024 + h * 64;
    qf[m][0] = *(const bf16x8*)(qp + quad * 8);
    qf[m][1] = *(const bf16x8*)(qp + 32 + quad * 8);
  }
  bf16x8 onesf;
#pragma unroll
  for (int j = 0; j < 8; ++j) onesf[j] = f2bf(1.0f);

  floatx4 acc[2][4];   // [q-subtile][dv-subtile]
  floatx4 ps[2];       // row sums
#pragma unroll
  for (int m = 0; m < 2; ++m) {
    ps[m] = (floatx4){0.f, 0.f, 0.f, 0.f};
#pragma unroll
    for (int t = 0; t < 4; ++t) acc[m][t] = (floatx4){0.f, 0.f, 0.f, 0.f};
  }

  // staging: 2 rounds x 256 thr x 16B per 64x64 tile
  bf16x8 kst[2], vst[2];
  auto load_kv = [&](int kt) {
    const int k0 = kt * 64;
#pragma unroll
    for (int it = 0; it < 2; ++it) {
      int idx = it * 256 + tid, r = idx >> 3, c8 = idx & 7;
      kst[it] = *(const bf16x8*)(kk + (bS + k0 + r) * 64 + c8 * 8);
      vst[it] = *(const bf16x8*)(vt + (size_t)r * BStot + bS + k0 + c8 * 8);
    }
  };
  auto write_kv = [&](int buf) {
#pragma unroll
    for (int it = 0; it < 2; ++it) {
      int idx = it * 256 + tid, r = idx >> 3, c8 = idx & 7;
      int addr = r * 64 + ((c8 ^ (r & 7)) * 8);
      *(bf16x8*)&k_lds[buf][addr] = kst[it];
      *(bf16x8*)&v_lds[buf][addr] = vst[it];
    }
  };

  load_kv(kt0);
  write_kv(kt0 & 1);
  __syncthreads();

  for (int kt = kt0; kt < kt1; ++kt) {
    const int cur = kt & 1;
    if (kt + 1 < kt1) load_kv(kt + 1);  // prefetch into registers
    const bool diag = (kt == ktmax);

    // S^T = K.Q^T per kj-subtile t; K A-frags reused for 2 q-subtiles
#pragma unroll
    for (int t = 0; t < 4; ++t) {
      const bf16_t* kb = &k_lds[cur][(t * 16 + lm) * 64];
      bf16x8 a0 = *(const bf16x8*)(kb + ((quad ^ sw) * 8));
      bf16x8 a1 = *(const bf16x8*)(kb + (((4 + quad) ^ sw) * 8));
      floatx4 sv[2];
#pragma unroll
      for (int m = 0; m < 2; ++m) {
        floatx4 cc = (floatx4){0.f, 0.f, 0.f, 0.f};
        cc = __builtin_amdgcn_mfma_f32_16x16x32_bf16(a0, qf[m][0], cc, 0, 0, 0);
        cc = __builtin_amdgcn_mfma_f32_16x16x32_bf16(a1, qf[m][1], cc, 0, 0, 0);
        sv[m] = cc;
      }
      if (diag) {
#pragma unroll
        for (int m = 0; m < 2; ++m) {
          int qq = qoff + m * 16 + lm;
#pragma unroll
          for (int r = 0; r < 4; ++r) {
            int kj = t * 16 + quad * 4 + r;
            sv[m][r] = (kj <= qq) ? __expf(sv[m][r]) : 0.f;
          }
        }
      } else {
#pragma unroll
        for (int m = 0; m < 2; ++m)
#pragma unroll
          for (int r = 0; r < 4; ++r) sv[m][r] = __expf(sv[m][r]);
      }
      // P^T (C-layout) -> p_lds in swizzled A-layout
#pragma unroll
      for (int m = 0; m < 2; ++m) {
        bf16x4 pk;
#pragma unroll
        for (int r = 0; r < 4; ++r) pk[r] = f2bf(sv[m][r]);
        *(bf16x4*)&p_lds[wave][(m * 16 + lm) * 64 +
                               (((2 * t + (quad >> 1)) ^ sw) * 8) + (quad & 1) * 4] = pk;
      }
    }
    // P A-frags (wave-private LDS, same-wave in-order: no barrier)
    bf16x8 p0[2], p1[2];
#pragma unroll
    for (int m = 0; m < 2; ++m) {
      const bf16_t* pb = &p_lds[wave][(m * 16 + lm) * 64];
      p0[m] = *(const bf16x8*)(pb + ((quad ^ sw) * 8));
      p1[m] = *(const bf16x8*)(pb + (((4 + quad) ^ sw) * 8));
      ps[m] = __builtin_amdgcn_mfma_f32_16x16x32_bf16(p0[m], onesf, ps[m], 0, 0, 0);
      ps[m] = __builtin_amdgcn_mfma_f32_16x16x32_bf16(p1[m], onesf, ps[m], 0, 0, 0);
    }
    // O += P.V : V B-frags reused for 2 q-subtiles
#pragma unroll
    for (int t = 0; t < 4; ++t) {
      const bf16_t* vb = &v_lds[cur][(t * 16 + lm) * 64];
      bf16x8 v0 = *(const bf16x8*)(vb + ((quad ^ sw) * 8));
      bf16x8 v1 = *(const bf16x8*)(vb + (((4 + quad) ^ sw) * 8));
#pragma unroll
      for (int m = 0; m < 2; ++m) {
        acc[m][t] = __builtin_amdgcn_mfma_f32_16x16x32_bf16(p0[m], v0, acc[m][t], 0, 0, 0);
        acc[m][t] = __builtin_amdgcn_mfma_f32_16x16x32_bf16(p1[m], v1, acc[m][t], 0, 0, 0);
      }
    }
    if (kt + 1 < kt1) write_kv(1 - cur);
    __syncthreads();
  }

  // epilogue: write raw partials into slot s
  const size_t slotO = (size_t)BStot * 1024;
  const size_t slotL = (size_t)BStot * 16;
#pragma unroll
  for (int m = 0; m < 2; ++m) {
    const int q0 = qb + m * 16 + quad * 4;
#pragma unroll
    for (int t = 0; t < 4; ++t)
#pragma unroll
      for (int r = 0; r < 4; ++r)
        Opart[s * slotO + (bS + q0 + r) * 1024 + h * 64 + t * 16 + lm] =
            f2bf(acc[m][t][r]);
    if (lm == 0)
#pragma unroll
      for (int r = 0; r < 4; ++r)
        lpart[s * slotL + (bS + q0 + r) * 16 + h] = ps[m][r];
  }
  // s==0 block zeroes the nonexistent slots for its rows/head
  if (s == 0) {
    for (int ss = nchunks; ss < 4; ++ss) {
#pragma unroll
      for (int m = 0; m < 2; ++m) {
        const int q0 = qb + m * 16 + quad * 4;
#pragma unroll
        for (int t = 0; t < 4; ++t)
#pragma unroll
          for (int r = 0; r < 4; ++r)
            Opart[ss * slotO + (bS + q0 + r) * 1024 + h * 64 + t * 16 + lm] = f2bf(0.f);
        if (lm == 0)
#pragma unroll
          for (int r = 0; r < 4; ++r)
            lpart[ss * slotL + (bS + q0 + r) * 16 + h] = 0.f;
      }
    }
  }
}

// ---------- combine partials: Ob = (sum_s Opart) / (sum_s lpart) ----------
__global__ __launch_bounds__(256) void combine_o(const bf16_t* __restrict__ Opart,
                                                 const float* __restrict__ lpart,
                                                 bf16_t* __restrict__ Ob, int BS) {
  const int idx = (blockIdx.x * 256 + threadIdx.x) * 8;
  const int row = idx >> 10, col = idx & 1023, h = col >> 6;
  const size_t slotO = (size_t)BS * 1024;
  const size_t slotL = (size_t)BS * 16;
  float l = 0.f;
#pragma unroll
  for (int s = 0; s < 4; ++s) l += lpart[s * slotL + row * 16 + h];
  float o[8];
#pragma unroll
  for (int j = 0; j < 8; ++j) o[j] = 0.f;
#pragma unroll
  for (int s = 0; s < 4; ++s) {
    bf16x8 v = *(const bf16x8*)(Opart + s * slotO + idx);
#pragma unroll
    for (int j = 0; j < 8; ++j) o[j] += (float)v[j];
  }
  const float rl = 1.0f / l;
  bf16x8 out;
#pragma unroll
  for (int j = 0; j < 8; ++j) out[j] = f2bf(o[j] * rl);
  *(bf16x8*)(Ob + idx) = out;
}

// ---------- launcher ----------
extern "C" void kernel_launch(void* const* d_in, const int* in_sizes, int n_in,
                              void* d_out, int out_size, void* d_ws, size_t ws_size,
                              hipStream_t stream) {
  const float* Q  = (const float*)d_in[0];
  const float* K  = (const float*)d_in[1];
  const float* V  = (const float*)d_in[2];
  const float* Wq = (const float*)d_in[3];
  const float* Wk = (const float*)d_in[4];
  const float* Wv = (const float*)d_in[5];
  const float* Wo = (const float*)d_in[6];

  const int BS = in_sizes[0] / 1024;  // B*S = 4096
  const int B  = BS / S_LEN;

  bf16_t* ws  = (bf16_t*)d_ws;
  bf16_t* qp  = ws;                              // q proj [BS,1024] (pre-scaled 1/8)
  bf16_t* Ob  = qp  + (size_t)BS * 1024;         // attn out [BS,1024]
  bf16_t* Wqt = Ob  + (size_t)BS * 1024;         // [1024,1024] (N,K)
  bf16_t* Wot = Wqt + (size_t)1024 * 1024;
  bf16_t* Wkt = Wot + (size_t)1024 * 1024;       // [64,1024]
  bf16_t* Wvt = Wkt + (size_t)64 * 1024;
  bf16_t* kp  = Wvt + (size_t)64 * 1024;         // [BS,64]
  bf16_t* vpt = kp  + (size_t)BS * 64;           // [64,BS]
  bf16_t* Opart = vpt + (size_t)BS * 64;         // 4 x [BS,1024] bf16 (32 MB)
  float*  lpart = (float*)(Opart + (size_t)4 * BS * 1024);  // 4 x [BS,16] f32

  // 1) all weight transposes
  transpose_all<<<2176, 256, 0, stream>>>(Wq, Wo, Wk, Wv, Wqt, Wot, Wkt, Wvt);

  // 2) Q-proj + K-proj + V-proj (640 blocks, co-scheduled)
  proj_all<<<(BS / 64) * 8 + (BS / 64) * 2, 256, 0, stream>>>(
      Q, K, V, Wqt, Wkt, Wvt, qp, kp, vpt, BS);

  // 3) flash attention, k-chunked: 160 chunk-slots x 4 head-groups x B
  flash_mqa<<<dim3(160, NHEAD / 4, B), 256, 0, stream>>>(qp, kp, vpt, Opart, lpart, BS);

  // 4) combine partials -> Ob
  combine_o<<<(BS * 1024) / (256 * 8), 256, 0, stream>>>(Opart, lpart, Ob, BS);

  // 5) O-proj (f32 out)
  gemm_oproj<<<dim3(BS / 64, 8), 256, 0, stream>>>(Ob, Wot, (float*)d_out, BS, 1024, 1024);
}